// Round 10
// baseline (1709.994 us; speedup 1.0000x reference)
//
#include <hip/hip_runtime.h>
#include <math.h>
#include <stdint.h>

// Greedy DPP MAP — persistent kernel, round 10.
// N=8192, D=512, K=256. 256 blocks x 256 threads (1 block/CU); 8 lanes/row.
// vs round 9: tail restructure — per-WAVE early publish.
//  - 1024 partial slots (one per wave, 64B line each). After C, each wave
//    shuffle-reduces its 8 rows and lane0 publishes IMMEDIATELY: no S3
//    barrier, no block reduce, no vmcnt(0) drain before publish.
//  - e-store visibility is guaranteed by pipeline slack: reader consumes
//    cisT[j] only after detecting ALL 1024 partials + reduce + read RTT
//    (>=~2100cy after winner's partial), while the winner's e-store entered
//    the same VMEM path ~150cy earlier. (FN init keeps its one-time drain.)
//  - A-phase: all 4 waves poll (256 lines each, 4/lane), butterfly, S1,
//    then EVERY thread combines the 4 wave winners locally.
// fn_j / cisT[j] remain PLAIN CACHED loads (write-once / read-once-fresh);
// e-stores / FN-init / partial publishes remain sc0+sc1 bypass.
// No fences / ordered atomics anywhere.

#define N 8192
#define D 512
#define K 256
#define LAMBDA_REG 0.01f
#define NBLK 256
#define NTHR 256
#define NWAVE 1024       // total waves = partial slots
#define ROWS 32          // rows per block
#define RS   560         // floats per row in lds_fn
#define CS   68          // floats per 64-float chunk (64 + 4 pad)
#define CTS  264         // floats per row in lds_ct
#define SSTR 8           // u64s per slot line (64B)
#define SCOPE __HIP_MEMORY_SCOPE_AGENT

typedef unsigned long long u64;
typedef float f32x4 __attribute__((ext_vector_type(4)));

struct __align__(8) Pick { float v; int i; };

__device__ __forceinline__ bool better(float av, int ai, float bv, int bi) {
    // first-max semantics (jnp.argmax tie-break: lowest index wins)
    return (av > bv) || (av == bv && ai < bi);
}

__device__ __forceinline__ u64 pack_slot(float v, int idx, int tag) {
    unsigned hi = ((unsigned)tag << 13) | (unsigned)idx;   // idx < 8192
    return ((u64)hi << 32) | (u64)__float_as_uint(v);
}

__device__ __forceinline__ void bypass_store_u64(u64* p, u64 v) {
    asm volatile("global_store_dwordx2 %0, %1, off sc0 sc1"
                 :: "v"(p), "v"(v) : "memory");
}

__device__ __forceinline__ void bypass_store_f32x4(const f32x4* p, f32x4 v) {
    asm volatile("global_store_dwordx4 %0, %1, off sc0 sc1"
                 :: "v"(p), "v"(v) : "memory");
}

__global__ __launch_bounds__(NTHR, 1) void dpp_kernel(
        const float* __restrict__ F, const float* __restrict__ q,
        float* __restrict__ FN, float* __restrict__ cisT,
        u64* __restrict__ slots, int* __restrict__ out)
{
    const int tid  = threadIdx.x;
    const int blk  = blockIdx.x;
    const int wid  = tid >> 6;        // wave 0..3
    const int lane = tid & 63;
    const int r    = tid >> 3;        // local row 0..31
    const int c    = tid & 7;         // chunk lane 0..7
    const int n    = blk * ROWS + r;  // global row
    const int gw   = blk * 4 + wid;   // global wave id = partial slot idx

    __shared__ __align__(16) float lds_fn[ROWS * RS];   // own FN rows
    __shared__ __align__(16) float lds_ct[ROWS * CTS];  // own cis prefix
    __shared__ __align__(16) float lds_gj[8 * CS];      // fn_j staged
    __shared__ __align__(16) float lds_cj[K];           // cisT[j][0..t)
    __shared__ Pick lds_wave[4];

    const f32x4* F4  = reinterpret_cast<const f32x4*>(F);
    f32x4*       FN4 = reinterpret_cast<f32x4*>(FN);

    // ---- init: load own row, normalize; FN written via MALL-bypass stores ----
    float dloc, qn;
    bool  masked = false;
    {
        const f32x4* src = F4 + (size_t)n * (D / 4) + c * 16;
        float* frow = &lds_fn[r * RS + c * CS];
        float ss = 0.f;
        #pragma unroll
        for (int i = 0; i < 16; ++i) {
            f32x4 v = src[i];
            *reinterpret_cast<f32x4*>(frow + 4 * i) = v;
            ss = fmaf(v.x, v.x, ss); ss = fmaf(v.y, v.y, ss);
            ss = fmaf(v.z, v.z, ss); ss = fmaf(v.w, v.w, ss);
        }
        ss += __shfl_xor(ss, 1); ss += __shfl_xor(ss, 2); ss += __shfl_xor(ss, 4);
        const float norm = sqrtf(ss);
        f32x4* dst = FN4 + (size_t)n * (D / 4) + c * 16;
        float ssn = 0.f;
        #pragma unroll
        for (int i = 0; i < 16; ++i) {
            f32x4 v = *reinterpret_cast<f32x4*>(frow + 4 * i);
            v.x /= norm; v.y /= norm; v.z /= norm; v.w /= norm;
            *reinterpret_cast<f32x4*>(frow + 4 * i) = v;
            bypass_store_f32x4(dst + i, v);
            ssn = fmaf(v.x, v.x, ssn); ssn = fmaf(v.y, v.y, ssn);
            ssn = fmaf(v.z, v.z, ssn); ssn = fmaf(v.w, v.w, ssn);
        }
        ssn += __shfl_xor(ssn, 1); ssn += __shfl_xor(ssn, 2); ssn += __shfl_xor(ssn, 4);
        qn = q[n];
        dloc = fmaf(sqrtf(qn * qn), ssn, LAMBDA_REG);
    }

    // ---- initial per-wave partial (tag 0, buffer 0) — safe drain once ----
    {
        float v = dloc; int idx = n;
        #pragma unroll
        for (int m = 32; m > 0; m >>= 1) {
            float ov = __shfl_xor(v, m);
            int   oi = __shfl_xor(idx, m);
            if (better(ov, oi, v, idx)) { v = ov; idx = oi; }
        }
        asm volatile("s_waitcnt vmcnt(0)" ::: "memory");  // wave's FN stores at MALL
        if (lane == 0)
            bypass_store_u64(&slots[gw * SSTR], pack_slot(v, idx, 0));
    }

    for (int t = 0; t < K; ++t) {
        const unsigned want = (unsigned)t;

        // ---- A: each wave polls its 256-line slice of the 1024 partials ----
        {
            const u64* pb = slots + (t & 1) * NWAVE * SSTR;
            const int s0 = wid * 256 + lane * 4;
            u64 x0, x1, x2, x3;
            while (true) {
                x0 = __hip_atomic_load(pb + (s0 + 0) * SSTR, __ATOMIC_RELAXED, SCOPE);
                x1 = __hip_atomic_load(pb + (s0 + 1) * SSTR, __ATOMIC_RELAXED, SCOPE);
                x2 = __hip_atomic_load(pb + (s0 + 2) * SSTR, __ATOMIC_RELAXED, SCOPE);
                x3 = __hip_atomic_load(pb + (s0 + 3) * SSTR, __ATOMIC_RELAXED, SCOPE);
                bool ok = ((unsigned)(x0 >> 45) == want) &&
                          ((unsigned)(x1 >> 45) == want) &&
                          ((unsigned)(x2 >> 45) == want) &&
                          ((unsigned)(x3 >> 45) == want);
                if (__all(ok)) break;
                __builtin_amdgcn_s_sleep(1);
            }
            asm volatile("" ::: "memory");
            float v = __uint_as_float((unsigned)x0);
            int idx = (int)((x0 >> 32) & 8191u);
            {
                float w = __uint_as_float((unsigned)x1); int k1 = (int)((x1 >> 32) & 8191u);
                if (better(w, k1, v, idx)) { v = w; idx = k1; }
                w = __uint_as_float((unsigned)x2); k1 = (int)((x2 >> 32) & 8191u);
                if (better(w, k1, v, idx)) { v = w; idx = k1; }
                w = __uint_as_float((unsigned)x3); k1 = (int)((x3 >> 32) & 8191u);
                if (better(w, k1, v, idx)) { v = w; idx = k1; }
            }
            #pragma unroll
            for (int m = 32; m > 0; m >>= 1) {
                float ov = __shfl_xor(v, m);
                int   oi = __shfl_xor(idx, m);
                if (better(ov, oi, v, idx)) { v = ov; idx = oi; }
            }
            if (lane == 0) { lds_wave[wid].v = v; lds_wave[wid].i = idx; }
        }
        __syncthreads();                              // S1
        // every thread combines the 4 wave winners (no extra hop)
        float dj; int j;
        {
            Pick p = lds_wave[0];
            #pragma unroll
            for (int w = 1; w < 4; ++w) {
                Pick o = lds_wave[w];
                if (better(o.v, o.i, p.v, p.i)) p = o;
            }
            dj = p.v; j = p.i;
        }

        if (blk == 0 && tid == 0) out[t] = j;
        if (t == K - 1) break;

        const float sj = sqrtf(dj);
        const float qj = q[j];

        // ---- B: parallel staging — waves 0-1: fn_j; waves 2-3: cisT[j] ----
        f32x4 gv;
        float cv0, cv1;
        int   tt0 = tid - 128, tt1 = tid;
        if (tid < 128) {
            gv = FN4[(size_t)j * (D / 4) + tid];
        } else {
            if (tt0 < t) cv0 = cisT[(size_t)j * K + tt0];
            if (tt1 < t) cv1 = cisT[(size_t)j * K + tt1];
        }
        if (tid < 128) {
            *reinterpret_cast<f32x4*>(&lds_gj[(tid >> 4) * CS + (tid & 15) * 4]) = gv;
        } else {
            if (tt0 < t) lds_cj[tt0] = cv0;
            if (tt1 < t) lds_cj[tt1] = cv1;
        }
        __syncthreads();                              // S2

        // ---- C: dot (LDS x LDS), cd, e, updates ----
        const float* frow = &lds_fn[r * RS + c * CS];
        const float* grow = &lds_gj[c * CS];
        f32x4 a = {0.f, 0.f, 0.f, 0.f};
        #pragma unroll
        for (int i = 0; i < 16; ++i) {
            f32x4 v = *reinterpret_cast<const f32x4*>(frow + 4 * i);
            f32x4 g = *reinterpret_cast<const f32x4*>(grow + 4 * i);
            a.x = fmaf(v.x, g.x, a.x); a.y = fmaf(v.y, g.y, a.y);
            a.z = fmaf(v.z, g.z, a.z); a.w = fmaf(v.w, g.w, a.w);
        }
        float dot = (a.x + a.y) + (a.z + a.w);
        dot += __shfl_xor(dot, 1); dot += __shfl_xor(dot, 2); dot += __shfl_xor(dot, 4);
        float Ljn = sqrtf(qj * qn) * dot;
        if (n == j) Ljn += LAMBDA_REG;

        float cd = 0.f;
        const float* ctrow = &lds_ct[r * CTS];
        for (int tt = c; tt < t; tt += 8)
            cd = fmaf(lds_cj[tt], ctrow[tt], cd);
        cd += __shfl_xor(cd, 1); cd += __shfl_xor(cd, 2); cd += __shfl_xor(cd, 4);

        const float e = (Ljn - cd) / sj;
        if (c == 0) {
            lds_ct[r * CTS + t] = e;
            const float* ep = cisT + (size_t)n * K + t;
            asm volatile("global_store_dword %0, %1, off sc0 sc1"
                         :: "v"(ep), "v"(e) : "memory");     // issued early
        }
        dloc = fmaf(-e, e, dloc);
        if (n == j) masked = true;

        // ---- per-wave partial for t+1: shuffle reduce + IMMEDIATE publish ----
        {
            float v = masked ? -INFINITY : dloc; int idx = n;
            #pragma unroll
            for (int m = 32; m > 0; m >>= 1) {
                float ov = __shfl_xor(v, m);
                int   oi = __shfl_xor(idx, m);
                if (better(ov, oi, v, idx)) { v = ov; idx = oi; }
            }
            if (lane == 0)
                bypass_store_u64(&slots[(((t + 1) & 1) * NWAVE + gw) * SSTR],
                                 pack_slot(v, idx, t + 1));
        }
        // no S3 — waves proceed independently to the next poll
    }
}

extern "C" void kernel_launch(void* const* d_in, const int* in_sizes, int n_in,
                              void* d_out, int out_size, void* d_ws, size_t ws_size,
                              hipStream_t stream) {
    const float* F = (const float*)d_in[0];
    const float* q = (const float*)d_in[1];
    int* out = (int*)d_out;

    uint8_t* w = (uint8_t*)d_ws;
    u64*   slots = (u64*)(w + 4096);            // [2][1024] 64B lines = 128 KB
    float* FN    = (float*)(w + 262144);                       // 16 MB
    float* cisT  = (float*)(w + 262144 + (size_t)N * D * 4);   // 8 MB

    // invalidate all slot tags each launch (graph replays reuse ws)
    hipMemsetAsync((void*)w, 0xFF, 262144, stream);
    hipLaunchKernelGGL(dpp_kernel, dim3(NBLK), dim3(NTHR), 0, stream,
                       F, q, FN, cisT, slots, out);
}

// Round 11
// 1556.548 us; speedup vs baseline: 1.0986x; 1.0986x over previous
//
#include <hip/hip_runtime.h>
#include <math.h>
#include <stdint.h>

// Greedy DPP MAP — persistent kernel, round 11.
// N=8192, D=512, K=256. 256 blocks x 256 threads (1 block/CU); 8 lanes/row.
// vs round 9 (best, 1177us):
//  - S3 replaced by lgkmcnt(0) + raw s_barrier: no vmcnt(0) store-ack drain
//    on the critical path (r10 proved drain-free ordering is correct; store
//    acks are absorbed during the next ~1us poll window instead).
//  - own FN row lives in 16 NAMED f32x4 registers (no array -> no scratch);
//    fn_j read directly from cached global (L1/L2 broadcast, first-touch
//    fresh). lds_fn eliminated: C-phase LDS traffic halved, LDS 109->35KB.
//  - exchange unchanged from r9: wave0-only polls 256 spread 64B slot lines
//    (r10 showed 4x pollers = 4x FETCH = +45% time; wave0-only is right).
// e-stores / FN-init / publishes remain sc0+sc1 bypass (MALL-resident);
// fn_j / cisT[j] prefix are PLAIN CACHED loads (write-once-before-read,
// read-once-ever => never stale). No fences / ordered atomics anywhere.

#define N 8192
#define D 512
#define K 256
#define LAMBDA_REG 0.01f
#define NBLK 256
#define NTHR 256
#define ROWS 32          // rows per block
#define CTS  264         // floats per row in lds_ct (bank: 2-way max = free)
#define SSTR 8           // u64s per slot line (64B)
#define SCOPE __HIP_MEMORY_SCOPE_AGENT

typedef unsigned long long u64;
typedef float f32x4 __attribute__((ext_vector_type(4)));

struct __align__(8) Pick { float v; int i; };

__device__ __forceinline__ bool better(float av, int ai, float bv, int bi) {
    // first-max semantics (jnp.argmax tie-break: lowest index wins)
    return (av > bv) || (av == bv && ai < bi);
}

__device__ __forceinline__ u64 pack_slot(float v, int idx, int tag) {
    unsigned hi = ((unsigned)tag << 13) | (unsigned)idx;   // idx < 8192
    return ((u64)hi << 32) | (u64)__float_as_uint(v);
}

__device__ __forceinline__ void bypass_store_u64(u64* p, u64 v) {
    asm volatile("global_store_dwordx2 %0, %1, off sc0 sc1"
                 :: "v"(p), "v"(v) : "memory");
}

__device__ __forceinline__ void bypass_store_f32x4(const f32x4* p, f32x4 v) {
    asm volatile("global_store_dwordx4 %0, %1, off sc0 sc1"
                 :: "v"(p), "v"(v) : "memory");
}

__global__ __launch_bounds__(NTHR, 1) void dpp_kernel(
        const float* __restrict__ F, const float* __restrict__ q,
        float* __restrict__ FN, float* __restrict__ cisT,
        u64* __restrict__ slots, int* __restrict__ out)
{
    const int tid  = threadIdx.x;
    const int blk  = blockIdx.x;
    const int wid  = tid >> 6;        // wave 0..3
    const int lane = tid & 63;
    const int r    = tid >> 3;        // local row 0..31
    const int c    = tid & 7;         // chunk lane 0..7
    const int n    = blk * ROWS + r;  // global row

    __shared__ __align__(16) float lds_ct[ROWS * CTS];  // own cis prefix
    __shared__ __align__(16) float lds_cj[K];           // cisT[j][0..t)
    __shared__ Pick lds_wave[4];
    __shared__ Pick lds_final;

    const f32x4* F4  = reinterpret_cast<const f32x4*>(F);
    f32x4*       FN4 = reinterpret_cast<f32x4*>(FN);

    // ---- init: own 64-float chunk -> 16 NAMED f32x4 regs; normalize ----
    f32x4 v00, v01, v02, v03, v04, v05, v06, v07,
          v08, v09, v10, v11, v12, v13, v14, v15;
    float dloc, qn;
    bool  masked = false;
    {
        const f32x4* src = F4 + (size_t)n * (D / 4) + c * 16;
        v00 = src[0];  v01 = src[1];  v02 = src[2];  v03 = src[3];
        v04 = src[4];  v05 = src[5];  v06 = src[6];  v07 = src[7];
        v08 = src[8];  v09 = src[9];  v10 = src[10]; v11 = src[11];
        v12 = src[12]; v13 = src[13]; v14 = src[14]; v15 = src[15];
        float ss = 0.f;
#define ACC_SS(vv) ss = fmaf(vv.x, vv.x, ss); ss = fmaf(vv.y, vv.y, ss); \
                   ss = fmaf(vv.z, vv.z, ss); ss = fmaf(vv.w, vv.w, ss);
        ACC_SS(v00) ACC_SS(v01) ACC_SS(v02) ACC_SS(v03)
        ACC_SS(v04) ACC_SS(v05) ACC_SS(v06) ACC_SS(v07)
        ACC_SS(v08) ACC_SS(v09) ACC_SS(v10) ACC_SS(v11)
        ACC_SS(v12) ACC_SS(v13) ACC_SS(v14) ACC_SS(v15)
#undef ACC_SS
        ss += __shfl_xor(ss, 1); ss += __shfl_xor(ss, 2); ss += __shfl_xor(ss, 4);
        const float norm = sqrtf(ss);
#define NRM(vv) vv.x /= norm; vv.y /= norm; vv.z /= norm; vv.w /= norm;
        NRM(v00) NRM(v01) NRM(v02) NRM(v03) NRM(v04) NRM(v05) NRM(v06) NRM(v07)
        NRM(v08) NRM(v09) NRM(v10) NRM(v11) NRM(v12) NRM(v13) NRM(v14) NRM(v15)
#undef NRM
        float ssn = 0.f;
#define ACC_SSN(vv) ssn = fmaf(vv.x, vv.x, ssn); ssn = fmaf(vv.y, vv.y, ssn); \
                    ssn = fmaf(vv.z, vv.z, ssn); ssn = fmaf(vv.w, vv.w, ssn);
        ACC_SSN(v00) ACC_SSN(v01) ACC_SSN(v02) ACC_SSN(v03)
        ACC_SSN(v04) ACC_SSN(v05) ACC_SSN(v06) ACC_SSN(v07)
        ACC_SSN(v08) ACC_SSN(v09) ACC_SSN(v10) ACC_SSN(v11)
        ACC_SSN(v12) ACC_SSN(v13) ACC_SSN(v14) ACC_SSN(v15)
#undef ACC_SSN
        ssn += __shfl_xor(ssn, 1); ssn += __shfl_xor(ssn, 2); ssn += __shfl_xor(ssn, 4);
        f32x4* dst = FN4 + (size_t)n * (D / 4) + c * 16;
        bypass_store_f32x4(dst + 0,  v00); bypass_store_f32x4(dst + 1,  v01);
        bypass_store_f32x4(dst + 2,  v02); bypass_store_f32x4(dst + 3,  v03);
        bypass_store_f32x4(dst + 4,  v04); bypass_store_f32x4(dst + 5,  v05);
        bypass_store_f32x4(dst + 6,  v06); bypass_store_f32x4(dst + 7,  v07);
        bypass_store_f32x4(dst + 8,  v08); bypass_store_f32x4(dst + 9,  v09);
        bypass_store_f32x4(dst + 10, v10); bypass_store_f32x4(dst + 11, v11);
        bypass_store_f32x4(dst + 12, v12); bypass_store_f32x4(dst + 13, v13);
        bypass_store_f32x4(dst + 14, v14); bypass_store_f32x4(dst + 15, v15);
        qn = q[n];
        dloc = fmaf(sqrtf(qn * qn), ssn, LAMBDA_REG);
    }

    // ---- initial block partial (tag 0, buffer 0) — one-time safe drain ----
    {
        float v = dloc; int idx = n;
        #pragma unroll
        for (int m = 32; m > 0; m >>= 1) {
            float ov = __shfl_xor(v, m);
            int   oi = __shfl_xor(idx, m);
            if (better(ov, oi, v, idx)) { v = ov; idx = oi; }
        }
        if (lane == 0) { lds_wave[wid].v = v; lds_wave[wid].i = idx; }
        asm volatile("s_waitcnt vmcnt(0)" ::: "memory");  // FN stores at MALL
        __syncthreads();
        if (tid == 0) {
            Pick p = lds_wave[0];
            #pragma unroll
            for (int w = 1; w < 4; ++w) {
                Pick o = lds_wave[w];
                if (better(o.v, o.i, p.v, p.i)) p = o;
            }
            bypass_store_u64(&slots[blk * SSTR], pack_slot(p.v, p.i, 0));
        }
    }

    for (int t = 0; t < K; ++t) {
        const unsigned want = (unsigned)t;

        // ---- A: wave0 polls all 256 spread slot lines (4/lane) ----
        if (tid < 64) {
            const u64* pb = slots + (t & 1) * NBLK * SSTR;
            u64 x0, x1, x2, x3;
            while (true) {
                x0 = __hip_atomic_load(pb + (tid * 4 + 0) * SSTR, __ATOMIC_RELAXED, SCOPE);
                x1 = __hip_atomic_load(pb + (tid * 4 + 1) * SSTR, __ATOMIC_RELAXED, SCOPE);
                x2 = __hip_atomic_load(pb + (tid * 4 + 2) * SSTR, __ATOMIC_RELAXED, SCOPE);
                x3 = __hip_atomic_load(pb + (tid * 4 + 3) * SSTR, __ATOMIC_RELAXED, SCOPE);
                bool ok = ((unsigned)(x0 >> 45) == want) &&
                          ((unsigned)(x1 >> 45) == want) &&
                          ((unsigned)(x2 >> 45) == want) &&
                          ((unsigned)(x3 >> 45) == want);
                if (__all(ok)) break;
                __builtin_amdgcn_s_sleep(1);
            }
            asm volatile("" ::: "memory");
            float v = __uint_as_float((unsigned)x0);
            int idx = (int)((x0 >> 32) & 8191u);
            {
                float w = __uint_as_float((unsigned)x1); int k1 = (int)((x1 >> 32) & 8191u);
                if (better(w, k1, v, idx)) { v = w; idx = k1; }
                w = __uint_as_float((unsigned)x2); k1 = (int)((x2 >> 32) & 8191u);
                if (better(w, k1, v, idx)) { v = w; idx = k1; }
                w = __uint_as_float((unsigned)x3); k1 = (int)((x3 >> 32) & 8191u);
                if (better(w, k1, v, idx)) { v = w; idx = k1; }
            }
            #pragma unroll
            for (int m = 32; m > 0; m >>= 1) {
                float ov = __shfl_xor(v, m);
                int   oi = __shfl_xor(idx, m);
                if (better(ov, oi, v, idx)) { v = ov; idx = oi; }
            }
            if (tid == 0) { lds_final.v = v; lds_final.i = idx; }
        }
        __syncthreads();                              // S1 (drain empty here)
        const float dj = lds_final.v;
        const int   j  = lds_final.i;

        if (blk == 0 && tid == 0) out[t] = j;
        if (t == K - 1) break;

        const float sj = sqrtf(dj);
        const float qj = q[j];

        // ---- B: stage cisT[j][0..t) to LDS (plain cached, 1 elem/thread) ----
        if (tid < t) lds_cj[tid] = cisT[(size_t)j * K + tid];
        __syncthreads();                              // S2 (drain empty here)

        // ---- C: dot = regs x cached-global fn_j ----
        const f32x4* gj = FN4 + (size_t)j * (D / 4) + c * 16;
        f32x4 a = {0.f, 0.f, 0.f, 0.f};
#define DOT(vv, i) { f32x4 g = gj[i]; \
        a.x = fmaf(vv.x, g.x, a.x); a.y = fmaf(vv.y, g.y, a.y); \
        a.z = fmaf(vv.z, g.z, a.z); a.w = fmaf(vv.w, g.w, a.w); }
        DOT(v00, 0)  DOT(v01, 1)  DOT(v02, 2)  DOT(v03, 3)
        DOT(v04, 4)  DOT(v05, 5)  DOT(v06, 6)  DOT(v07, 7)
        DOT(v08, 8)  DOT(v09, 9)  DOT(v10, 10) DOT(v11, 11)
        DOT(v12, 12) DOT(v13, 13) DOT(v14, 14) DOT(v15, 15)
#undef DOT
        float dot = (a.x + a.y) + (a.z + a.w);
        dot += __shfl_xor(dot, 1); dot += __shfl_xor(dot, 2); dot += __shfl_xor(dot, 4);
        float Ljn = sqrtf(qj * qn) * dot;
        if (n == j) Ljn += LAMBDA_REG;

        float cd = 0.f;
        const float* ctrow = &lds_ct[r * CTS];
        for (int tt = c; tt < t; tt += 8)
            cd = fmaf(lds_cj[tt], ctrow[tt], cd);
        cd += __shfl_xor(cd, 1); cd += __shfl_xor(cd, 2); cd += __shfl_xor(cd, 4);

        const float e = (Ljn - cd) / sj;
        if (c == 0) {
            lds_ct[r * CTS + t] = e;
            const float* ep = cisT + (size_t)n * K + t;
            asm volatile("global_store_dword %0, %1, off sc0 sc1"
                         :: "v"(ep), "v"(e) : "memory");    // fire-and-forget
        }
        dloc = fmaf(-e, e, dloc);
        if (n == j) masked = true;

        // ---- block partial for t+1: NO vmcnt drain (S3 = raw barrier) ----
        {
            float v = masked ? -INFINITY : dloc; int idx = n;
            #pragma unroll
            for (int m = 32; m > 0; m >>= 1) {
                float ov = __shfl_xor(v, m);
                int   oi = __shfl_xor(idx, m);
                if (better(ov, oi, v, idx)) { v = ov; idx = oi; }
            }
            if (lane == 0) { lds_wave[wid].v = v; lds_wave[wid].i = idx; }
        }
        asm volatile("s_waitcnt lgkmcnt(0)" ::: "memory");  // LDS writes only
        __builtin_amdgcn_sched_barrier(0);
        __builtin_amdgcn_s_barrier();                       // S3 (no vmcnt!)
        __builtin_amdgcn_sched_barrier(0);
        if (tid == 0) {
            Pick p = lds_wave[0];
            #pragma unroll
            for (int w = 1; w < 4; ++w) {
                Pick o = lds_wave[w];
                if (better(o.v, o.i, p.v, p.i)) p = o;
            }
            bypass_store_u64(&slots[(((t + 1) & 1) * NBLK + blk) * SSTR],
                             pack_slot(p.v, p.i, t + 1));
        }
    }
}

extern "C" void kernel_launch(void* const* d_in, const int* in_sizes, int n_in,
                              void* d_out, int out_size, void* d_ws, size_t ws_size,
                              hipStream_t stream) {
    const float* F = (const float*)d_in[0];
    const float* q = (const float*)d_in[1];
    int* out = (int*)d_out;

    uint8_t* w = (uint8_t*)d_ws;
    u64*   slots = (u64*)(w + 4096);            // [2][256] 64B lines = 32 KB
    float* FN    = (float*)(w + 131072);                      // 16 MB
    float* cisT  = (float*)(w + 131072 + (size_t)N * D * 4);  // 8 MB

    // invalidate all slot tags each launch (graph replays reuse ws)
    hipMemsetAsync((void*)w, 0xFF, 65536, stream);
    hipLaunchKernelGGL(dpp_kernel, dim3(NBLK), dim3(NTHR), 0, stream,
                       F, q, FN, cisT, slots, out);
}

// Round 12
// 1181.959 us; speedup vs baseline: 1.4467x; 1.3169x over previous
//
#include <hip/hip_runtime.h>
#include <math.h>
#include <stdint.h>

// Greedy DPP MAP — persistent kernel, round 12 = round 9 + ONE change:
// S3 no longer drains vmcnt (raw s_barrier + lgkmcnt only). The per-step
// e-store becomes fire-and-forget; its MALL ack is absorbed during the next
// poll window instead of sitting on the serial chain before the publish.
// (r10 empirically validated drain-free ordering with even tighter spacing;
//  r11 bundled this with a register restructure that spilled — reverted.)
// Everything else identical to r9 (best: 1177us): 256x256, 8 lanes/row,
// lds_fn row cache, wave0-only poll of 256 spread 64B slot lines,
// parallel B staging, plain cached fn_j/cisT[j] reads, sc0sc1 bypass writes.

#define N 8192
#define D 512
#define K 256
#define LAMBDA_REG 0.01f
#define NBLK 256
#define NTHR 256
#define ROWS 32          // rows per block
#define RS   560         // floats per row in lds_fn
#define CS   68          // floats per 64-float chunk (64 + 4 pad)
#define CTS  264         // floats per row in lds_ct
#define SSTR 8           // u64s per slot line (64B)
#define SCOPE __HIP_MEMORY_SCOPE_AGENT

typedef unsigned long long u64;
typedef float f32x4 __attribute__((ext_vector_type(4)));

struct __align__(8) Pick { float v; int i; };

__device__ __forceinline__ bool better(float av, int ai, float bv, int bi) {
    // first-max semantics (jnp.argmax tie-break: lowest index wins)
    return (av > bv) || (av == bv && ai < bi);
}

__device__ __forceinline__ u64 pack_slot(float v, int idx, int tag) {
    unsigned hi = ((unsigned)tag << 13) | (unsigned)idx;   // idx < 8192
    return ((u64)hi << 32) | (u64)__float_as_uint(v);
}

__device__ __forceinline__ void bypass_store_u64(u64* p, u64 v) {
    asm volatile("global_store_dwordx2 %0, %1, off sc0 sc1"
                 :: "v"(p), "v"(v) : "memory");
}

__device__ __forceinline__ void bypass_store_f32x4(const f32x4* p, f32x4 v) {
    asm volatile("global_store_dwordx4 %0, %1, off sc0 sc1"
                 :: "v"(p), "v"(v) : "memory");
}

__global__ __launch_bounds__(NTHR, 1) void dpp_kernel(
        const float* __restrict__ F, const float* __restrict__ q,
        float* __restrict__ FN, float* __restrict__ cisT,
        u64* __restrict__ slots, int* __restrict__ out)
{
    const int tid = threadIdx.x;
    const int blk = blockIdx.x;
    const int r   = tid >> 3;        // local row 0..31
    const int c   = tid & 7;         // chunk lane 0..7
    const int n   = blk * ROWS + r;  // global row

    __shared__ __align__(16) float lds_fn[ROWS * RS];   // own FN rows
    __shared__ __align__(16) float lds_ct[ROWS * CTS];  // own cis prefix
    __shared__ __align__(16) float lds_gj[8 * CS];      // fn_j staged
    __shared__ __align__(16) float lds_cj[K];           // cisT[j][0..t)
    __shared__ Pick lds_wave[NTHR / 64];
    __shared__ Pick lds_final;

    const f32x4* F4  = reinterpret_cast<const f32x4*>(F);
    f32x4*       FN4 = reinterpret_cast<f32x4*>(FN);

    // ---- init: load own row, normalize; FN written via MALL-bypass stores ----
    float dloc, qn;
    bool  masked = false;
    {
        const f32x4* src = F4 + (size_t)n * (D / 4) + c * 16;
        float* frow = &lds_fn[r * RS + c * CS];
        float ss = 0.f;
        #pragma unroll
        for (int i = 0; i < 16; ++i) {
            f32x4 v = src[i];
            *reinterpret_cast<f32x4*>(frow + 4 * i) = v;
            ss = fmaf(v.x, v.x, ss); ss = fmaf(v.y, v.y, ss);
            ss = fmaf(v.z, v.z, ss); ss = fmaf(v.w, v.w, ss);
        }
        ss += __shfl_xor(ss, 1); ss += __shfl_xor(ss, 2); ss += __shfl_xor(ss, 4);
        const float norm = sqrtf(ss);
        f32x4* dst = FN4 + (size_t)n * (D / 4) + c * 16;
        float ssn = 0.f;
        #pragma unroll
        for (int i = 0; i < 16; ++i) {
            f32x4 v = *reinterpret_cast<f32x4*>(frow + 4 * i);
            v.x /= norm; v.y /= norm; v.z /= norm; v.w /= norm;
            *reinterpret_cast<f32x4*>(frow + 4 * i) = v;
            bypass_store_f32x4(dst + i, v);
            ssn = fmaf(v.x, v.x, ssn); ssn = fmaf(v.y, v.y, ssn);
            ssn = fmaf(v.z, v.z, ssn); ssn = fmaf(v.w, v.w, ssn);
        }
        ssn += __shfl_xor(ssn, 1); ssn += __shfl_xor(ssn, 2); ssn += __shfl_xor(ssn, 4);
        qn = q[n];
        dloc = fmaf(sqrtf(qn * qn), ssn, LAMBDA_REG);
    }

    // ---- initial block partial (tag 0, buffer 0) — one-time safe drain ----
    {
        float v = dloc; int idx = n;
        #pragma unroll
        for (int m = 32; m > 0; m >>= 1) {
            float ov = __shfl_xor(v, m);
            int   oi = __shfl_xor(idx, m);
            if (better(ov, oi, v, idx)) { v = ov; idx = oi; }
        }
        if ((tid & 63) == 0) { lds_wave[tid >> 6].v = v; lds_wave[tid >> 6].i = idx; }
        asm volatile("s_waitcnt vmcnt(0)" ::: "memory");  // own FN stores at MALL
        __syncthreads();
        if (tid == 0) {
            Pick p = lds_wave[0];
            #pragma unroll
            for (int w = 1; w < NTHR / 64; ++w) {
                Pick o = lds_wave[w];
                if (better(o.v, o.i, p.v, p.i)) p = o;
            }
            bypass_store_u64(&slots[blk * SSTR], pack_slot(p.v, p.i, 0));
        }
    }

    for (int t = 0; t < K; ++t) {
        const unsigned want = (unsigned)t;

        // ---- A: wave0 polls all 256 spread slot lines (4/lane) ----
        if (tid < 64) {
            const u64* pb = slots + (t & 1) * NBLK * SSTR;
            u64 x0, x1, x2, x3;
            while (true) {
                x0 = __hip_atomic_load(pb + (tid * 4 + 0) * SSTR, __ATOMIC_RELAXED, SCOPE);
                x1 = __hip_atomic_load(pb + (tid * 4 + 1) * SSTR, __ATOMIC_RELAXED, SCOPE);
                x2 = __hip_atomic_load(pb + (tid * 4 + 2) * SSTR, __ATOMIC_RELAXED, SCOPE);
                x3 = __hip_atomic_load(pb + (tid * 4 + 3) * SSTR, __ATOMIC_RELAXED, SCOPE);
                bool ok = ((unsigned)(x0 >> 45) == want) &&
                          ((unsigned)(x1 >> 45) == want) &&
                          ((unsigned)(x2 >> 45) == want) &&
                          ((unsigned)(x3 >> 45) == want);
                if (__all(ok)) break;
                __builtin_amdgcn_s_sleep(1);
            }
            asm volatile("" ::: "memory");
            float v = __uint_as_float((unsigned)x0);
            int idx = (int)((x0 >> 32) & 8191u);
            {
                float w = __uint_as_float((unsigned)x1); int k1 = (int)((x1 >> 32) & 8191u);
                if (better(w, k1, v, idx)) { v = w; idx = k1; }
                w = __uint_as_float((unsigned)x2); k1 = (int)((x2 >> 32) & 8191u);
                if (better(w, k1, v, idx)) { v = w; idx = k1; }
                w = __uint_as_float((unsigned)x3); k1 = (int)((x3 >> 32) & 8191u);
                if (better(w, k1, v, idx)) { v = w; idx = k1; }
            }
            #pragma unroll
            for (int m = 32; m > 0; m >>= 1) {
                float ov = __shfl_xor(v, m);
                int   oi = __shfl_xor(idx, m);
                if (better(ov, oi, v, idx)) { v = ov; idx = oi; }
            }
            if (tid == 0) { lds_final.v = v; lds_final.i = idx; }
        }
        __syncthreads();                              // S1
        const float dj = lds_final.v;
        const int   j  = lds_final.i;

        if (blk == 0 && tid == 0) out[t] = j;
        if (t == K - 1) break;

        const float sj = sqrtf(dj);
        const float qj = q[j];

        // ---- B: parallel staging — waves 0-1: fn_j; waves 2-3: cisT[j] ----
        f32x4 gv;
        float cv0, cv1;
        int   tt0 = tid - 128, tt1 = tid;
        if (tid < 128) {
            gv = FN4[(size_t)j * (D / 4) + tid];
        } else {
            if (tt0 < t) cv0 = cisT[(size_t)j * K + tt0];
            if (tt1 < t) cv1 = cisT[(size_t)j * K + tt1];
        }
        if (tid < 128) {
            *reinterpret_cast<f32x4*>(&lds_gj[(tid >> 4) * CS + (tid & 15) * 4]) = gv;
        } else {
            if (tt0 < t) lds_cj[tt0] = cv0;
            if (tt1 < t) lds_cj[tt1] = cv1;
        }
        __syncthreads();                              // S2

        // ---- C: dot (LDS x LDS), cd, e, updates ----
        const float* frow = &lds_fn[r * RS + c * CS];
        const float* grow = &lds_gj[c * CS];
        f32x4 a = {0.f, 0.f, 0.f, 0.f};
        #pragma unroll
        for (int i = 0; i < 16; ++i) {
            f32x4 v = *reinterpret_cast<const f32x4*>(frow + 4 * i);
            f32x4 g = *reinterpret_cast<const f32x4*>(grow + 4 * i);
            a.x = fmaf(v.x, g.x, a.x); a.y = fmaf(v.y, g.y, a.y);
            a.z = fmaf(v.z, g.z, a.z); a.w = fmaf(v.w, g.w, a.w);
        }
        float dot = (a.x + a.y) + (a.z + a.w);
        dot += __shfl_xor(dot, 1); dot += __shfl_xor(dot, 2); dot += __shfl_xor(dot, 4);
        float Ljn = sqrtf(qj * qn) * dot;
        if (n == j) Ljn += LAMBDA_REG;

        float cd = 0.f;
        const float* ctrow = &lds_ct[r * CTS];
        for (int tt = c; tt < t; tt += 8)
            cd = fmaf(lds_cj[tt], ctrow[tt], cd);
        cd += __shfl_xor(cd, 1); cd += __shfl_xor(cd, 2); cd += __shfl_xor(cd, 4);

        const float e = (Ljn - cd) / sj;
        if (c == 0) {
            lds_ct[r * CTS + t] = e;
            const float* ep = cisT + (size_t)n * K + t;
            asm volatile("global_store_dword %0, %1, off sc0 sc1"
                         :: "v"(ep), "v"(e) : "memory");    // fire-and-forget
        }
        dloc = fmaf(-e, e, dloc);
        if (n == j) masked = true;

        // ---- block partial for t+1; S3 = raw barrier, NO vmcnt drain ----
        {
            float v = masked ? -INFINITY : dloc; int idx = n;
            #pragma unroll
            for (int m = 32; m > 0; m >>= 1) {
                float ov = __shfl_xor(v, m);
                int   oi = __shfl_xor(idx, m);
                if (better(ov, oi, v, idx)) { v = ov; idx = oi; }
            }
            if ((tid & 63) == 0) { lds_wave[tid >> 6].v = v; lds_wave[tid >> 6].i = idx; }
        }
        asm volatile("s_waitcnt lgkmcnt(0)" ::: "memory");  // LDS writes only
        __builtin_amdgcn_sched_barrier(0);
        __builtin_amdgcn_s_barrier();                       // S3 (no vmcnt!)
        __builtin_amdgcn_sched_barrier(0);
        if (tid == 0) {
            Pick p = lds_wave[0];
            #pragma unroll
            for (int w = 1; w < NTHR / 64; ++w) {
                Pick o = lds_wave[w];
                if (better(o.v, o.i, p.v, p.i)) p = o;
            }
            bypass_store_u64(&slots[(((t + 1) & 1) * NBLK + blk) * SSTR],
                             pack_slot(p.v, p.i, t + 1));
        }
    }
}

extern "C" void kernel_launch(void* const* d_in, const int* in_sizes, int n_in,
                              void* d_out, int out_size, void* d_ws, size_t ws_size,
                              hipStream_t stream) {
    const float* F = (const float*)d_in[0];
    const float* q = (const float*)d_in[1];
    int* out = (int*)d_out;

    uint8_t* w = (uint8_t*)d_ws;
    u64*   slots = (u64*)(w + 4096);            // [2][256] 64B lines = 32 KB
    float* FN    = (float*)(w + 131072);                      // 16 MB
    float* cisT  = (float*)(w + 131072 + (size_t)N * D * 4);  // 8 MB

    // invalidate all slot tags each launch (graph replays reuse ws)
    hipMemsetAsync((void*)w, 0xFF, 65536, stream);
    hipLaunchKernelGGL(dpp_kernel, dim3(NBLK), dim3(NTHR), 0, stream,
                       F, q, FN, cisT, slots, out);
}